// Round 3
// baseline (1255.221 us; speedup 1.0000x reference)
//
#include <hip/hip_runtime.h>
#include <hip/hip_bf16.h>
#include <stdint.h>

// Problem constants (from reference)
#define M_DIM 16384   // 4 * 4096 rows of x
#define K_DIM 4096    // in_features
#define N_DIM 4096    // out_features
#define NGROUPS (N_DIM * (K_DIM / 8))  // 2,097,152 (o, in-group) tasks

// GEMM tile config (m97 structure: 128x128 tile, BK=64, 4 waves, 2-barrier loop)
#define BM 128
#define BN 128
#define BK 64

typedef short  s16x8 __attribute__((ext_vector_type(8)));
typedef float  f32x4 __attribute__((ext_vector_type(4)));
typedef unsigned short ushort_t;

__device__ __forceinline__ ushort_t f2bf(float f) {
  union { float f; uint32_t u; } v; v.f = f;
  uint32_t u = v.u;
  uint32_t r = (u + 0x7FFFu + ((u >> 16) & 1u)) >> 16;  // RNE bf16
  return (ushort_t)r;
}

// ---------------- Prepass 1: x (f32) -> bf16, [M][K] row-major ----------------
__global__ void cvt_x_kernel(const float* __restrict__ x, ushort_t* __restrict__ xh, int n8) {
  int i = blockIdx.x * blockDim.x + threadIdx.x;
  const int stride = gridDim.x * blockDim.x;
  for (; i < n8; i += stride) {
    const float4* p = (const float4*)(x + (size_t)i * 8);
    float4 a = p[0], b = p[1];
    ushort_t o[8];
    o[0] = f2bf(a.x); o[1] = f2bf(a.y); o[2] = f2bf(a.z); o[3] = f2bf(a.w);
    o[4] = f2bf(b.x); o[5] = f2bf(b.y); o[6] = f2bf(b.z); o[7] = f2bf(b.w);
    *(s16x8*)(xh + (size_t)i * 8) = *(s16x8*)o;
  }
}

// ---------------- Prepass 2: dequant W -> bf16, [N][K] row-major (B^T form) ----
// W[o][k] = cb0[codes[o][g][0]][k%8] + cb1[codes[o][g][1]][k%8]   (g = k/8)
// Per-o scale deferred to GEMM epilogue (exact: scale is linear per output col).
__global__ void dequant_w_kernel(const int* __restrict__ codes, const float* __restrict__ cb,
                                 ushort_t* __restrict__ wh) {
  int t = blockIdx.x * blockDim.x + threadIdx.x;   // t = o*512 + g
  if (t >= NGROUPS) return;
  int2 c = ((const int2*)codes)[t];
  const float4* e0 = (const float4*)(cb + (size_t)c.x * 8);          // codebook 0
  const float4* e1 = (const float4*)(cb + 2048 + (size_t)c.y * 8);   // codebook 1
  float4 a0 = e0[0], a1 = e0[1];
  float4 b0 = e1[0], b1 = e1[1];
  ushort_t o[8];
  o[0] = f2bf(a0.x + b0.x); o[1] = f2bf(a0.y + b0.y);
  o[2] = f2bf(a0.z + b0.z); o[3] = f2bf(a0.w + b0.w);
  o[4] = f2bf(a1.x + b1.x); o[5] = f2bf(a1.y + b1.y);
  o[6] = f2bf(a1.z + b1.z); o[7] = f2bf(a1.w + b1.w);
  *(s16x8*)(wh + (size_t)t * 8) = *(s16x8*)o;
}

// ---------------- Main GEMM: out = (x . W^T) * scale[n] + bias[n] --------------
// m97 structure + T1 XCD swizzle (1D grid, bijective: 4096 % 8 == 0).
// Template: XF32=false -> A is bf16 [M][K] (primary);
// XF32=true -> A is f32 x directly, converted to bf16 at fragment-load (fallback).
template<bool XF32>
__global__ void __launch_bounds__(256)
gemm_kernel(const void* __restrict__ Ax, const ushort_t* __restrict__ Bw,
            const float* __restrict__ scales, const float* __restrict__ bias,
            float* __restrict__ out) {
  __shared__ ushort_t As[XF32 ? BM * BK * 2 : BM * BK];  // 32 KB : 16 KB
  __shared__ ushort_t Bs[BN * BK];                       // 16 KB

  const int t    = threadIdx.x;
  const int lane = t & 63;
  const int wid  = t >> 6;
  const int wm   = wid >> 1;        // wave row (0..1) -> 64 rows each
  const int wn   = wid & 1;         // wave col (0..1) -> 64 cols each

  // T1: XCD-aware swizzle. nwg = 4096 (divisible by 8 -> simple form bijective).
  const int NTN  = N_DIM / BN;                   // 32 tiles in N
  const int nwg  = NTN * (M_DIM / BM);           // 4096
  const int cpx  = nwg >> 3;                     // 512 blocks per XCD chunk
  const int orig = blockIdx.x;
  const int swz  = (orig & 7) * cpx + (orig >> 3);
  const int tile_n = (swz % NTN) * BN;
  const int tile_m = (swz / NTN) * BM;

  f32x4 acc[4][4];
#pragma unroll
  for (int i = 0; i < 4; ++i)
#pragma unroll
    for (int j = 0; j < 4; ++j) acc[i][j] = (f32x4)0.0f;

  for (int k0 = 0; k0 < K_DIM; k0 += BK) {
    // ---- A staging ----
    if constexpr (XF32) {
      // f32 tile: 128 rows x 64 f32 = 32 KB; 8 rounds x 4 KB; 16 rows/round
      const float* Af = (const float*)Ax;
      const float* g = Af + (size_t)(tile_m + (t >> 4)) * K_DIM + (t & 15) * 4 + k0;
      float* l = (float*)As + (size_t)t * 4;
#pragma unroll
      for (int r = 0; r < 8; ++r)
        __builtin_amdgcn_global_load_lds(
            (const __attribute__((address_space(1))) void*)(g + (size_t)r * 16 * K_DIM),
            (__attribute__((address_space(3))) void*)(l + r * 1024), 16, 0, 0);
    } else {
      // bf16 tile: 128 rows x 64 bf16 = 16 KB; 4 rounds x 4 KB; 32 rows/round
      const ushort_t* A16 = (const ushort_t*)Ax;
      const ushort_t* g = A16 + (size_t)(tile_m + (t >> 3)) * K_DIM + (t & 7) * 8 + k0;
      ushort_t* l = As + (size_t)t * 8;
#pragma unroll
      for (int r = 0; r < 4; ++r)
        __builtin_amdgcn_global_load_lds(
            (const __attribute__((address_space(1))) void*)(g + (size_t)r * 32 * K_DIM),
            (__attribute__((address_space(3))) void*)(l + r * 2048), 16, 0, 0);
    }
    // ---- B staging (bf16 always) ----
    {
      const ushort_t* g = Bw + (size_t)(tile_n + (t >> 3)) * K_DIM + (t & 7) * 8 + k0;
      ushort_t* l = Bs + (size_t)t * 8;
#pragma unroll
      for (int r = 0; r < 4; ++r)
        __builtin_amdgcn_global_load_lds(
            (const __attribute__((address_space(1))) void*)(g + (size_t)r * 32 * K_DIM),
            (__attribute__((address_space(3))) void*)(l + r * 2048), 16, 0, 0);
    }
    __syncthreads();  // drains vmcnt: tiles resident

#pragma unroll
    for (int ks = 0; ks < 2; ++ks) {
      const int kof = ks * 32 + (lane >> 4) * 8;   // element offset in K within tile
      s16x8 a[4], b[4];
#pragma unroll
      for (int i = 0; i < 4; ++i) {
        const int row = wm * 64 + i * 16 + (lane & 15);
        if constexpr (XF32) {
          const float* pr = (const float*)As + (size_t)row * BK + kof;
          f32x4 lo = *(const f32x4*)pr, hi = *(const f32x4*)(pr + 4);
          ushort_t tmp[8];
          tmp[0] = f2bf(lo[0]); tmp[1] = f2bf(lo[1]); tmp[2] = f2bf(lo[2]); tmp[3] = f2bf(lo[3]);
          tmp[4] = f2bf(hi[0]); tmp[5] = f2bf(hi[1]); tmp[6] = f2bf(hi[2]); tmp[7] = f2bf(hi[3]);
          a[i] = *(s16x8*)tmp;
        } else {
          a[i] = *(const s16x8*)&As[(size_t)row * BK + kof];
        }
      }
#pragma unroll
      for (int j = 0; j < 4; ++j)
        b[j] = *(const s16x8*)&Bs[(size_t)(wn * 64 + j * 16 + (lane & 15)) * BK + kof];
#pragma unroll
      for (int i = 0; i < 4; ++i)
#pragma unroll
        for (int j = 0; j < 4; ++j)
          acc[i][j] = __builtin_amdgcn_mfma_f32_16x16x32_bf16(a[i], b[j], acc[i][j], 0, 0, 0);
    }
    __syncthreads();  // compute done before next-tile overwrite
  }

  // epilogue: C/D layout col = lane&15, row = (lane>>4)*4 + r  (guide m89, verified)
#pragma unroll
  for (int j = 0; j < 4; ++j) {
    const int col = tile_n + wn * 64 + j * 16 + (lane & 15);
    const float s  = scales[col];
    const float bi = bias[col];
#pragma unroll
    for (int i = 0; i < 4; ++i) {
      const int row0 = tile_m + wm * 64 + i * 16 + (lane >> 4) * 4;
#pragma unroll
      for (int r = 0; r < 4; ++r)
        out[(size_t)(row0 + r) * N_DIM + col] = acc[i][j][r] * s + bi;
    }
  }
}

// ---------------- Last-resort fallback: direct dequant-dot (correct, slow) -----
__global__ void __launch_bounds__(256)
naive_kernel(const float* __restrict__ x, const int* __restrict__ codes,
             const float* __restrict__ cb, const float* __restrict__ scales,
             const float* __restrict__ bias, float* __restrict__ out) {
  const int n = blockIdx.x;
  const int m = blockIdx.y * blockDim.x + threadIdx.x;
  const int2* cr = (const int2*)codes + (size_t)n * (K_DIM / 8);
  const float* xr = x + (size_t)m * K_DIM;
  float acc = 0.f;
  for (int g = 0; g < K_DIM / 8; ++g) {
    int2 c = cr[g];                       // uniform across block -> scalar load
    const float* e0 = cb + (size_t)c.x * 8;
    const float* e1 = cb + 2048 + (size_t)c.y * 8;
#pragma unroll
    for (int j = 0; j < 8; ++j) acc += xr[g * 8 + j] * (e0[j] + e1[j]);
  }
  out[(size_t)m * N_DIM + n] = acc * scales[n] + bias[n];
}

extern "C" void kernel_launch(void* const* d_in, const int* in_sizes, int n_in,
                              void* d_out, int out_size, void* d_ws, size_t ws_size,
                              hipStream_t stream) {
  const float* x      = (const float*)d_in[0];
  const int*   codes  = (const int*)d_in[1];
  const float* cbs    = (const float*)d_in[2];
  const float* scales = (const float*)d_in[3];
  const float* bias   = (const float*)d_in[4];
  float* out = (float*)d_out;

  const size_t W_ELEMS = (size_t)N_DIM * K_DIM;  //  16.8M bf16 = 33.6 MB
  const size_t X_ELEMS = (size_t)M_DIM * K_DIM;  //  67.1M bf16 = 134 MB
  const int    NWG     = (N_DIM / BN) * (M_DIM / BM);  // 4096

  if (ws_size >= (W_ELEMS + X_ELEMS) * sizeof(ushort_t)) {
    // Primary: both operands pre-converted to bf16.
    ushort_t* wh = (ushort_t*)d_ws;
    ushort_t* xh = wh + W_ELEMS;
    hipLaunchKernelGGL(dequant_w_kernel, dim3(NGROUPS / 256), dim3(256), 0, stream,
                       codes, cbs, wh);
    hipLaunchKernelGGL(cvt_x_kernel, dim3(2048), dim3(256), 0, stream,
                       x, xh, (int)(X_ELEMS / 8));
    hipLaunchKernelGGL((gemm_kernel<false>), dim3(NWG), dim3(256), 0, stream,
                       (const void*)xh, wh, scales, bias, out);
  } else if (ws_size >= W_ELEMS * sizeof(ushort_t)) {
    // Fallback: dequant W only; GEMM stages x as f32, converts at fragment load.
    ushort_t* wh = (ushort_t*)d_ws;
    hipLaunchKernelGGL(dequant_w_kernel, dim3(NGROUPS / 256), dim3(256), 0, stream,
                       codes, cbs, wh);
    hipLaunchKernelGGL((gemm_kernel<true>), dim3(NWG), dim3(256), 0, stream,
                       (const void*)x, wh, scales, bias, out);
  } else {
    // Emergency: direct computation, correct but slow.
    hipLaunchKernelGGL(naive_kernel, dim3(N_DIM, M_DIM / 256), dim3(256), 0, stream,
                       x, codes, cbs, scales, bias, out);
  }
}